// Round 5
// baseline (282.326 us; speedup 1.0000x reference)
//
#include <hip/hip_runtime.h>
#include <cstdint>

#define C_     512
#define HW_    784
#define B_     64
#define NPAIR  50176               // B_*HW_
#define BN_EPS 1e-5f

// Workspace layout:
//   [0, 32768)            : wbits   uint32[512][16]  (bit c%32 of word c/32 = 1 iff W[o][c] < 0)
//   [32768, 40960)        : params  float4[512]      {A2, C2, slope, bias}
//   [49152, 49152+3.2MB)  : abits_g uint32[16][NPAIR] (word-major activation bits)
#define ABITS_OFF 49152
#define WS_NEEDED (ABITS_OFF + (size_t)NPAIR * 16 * 4)

// Math folding:
//   scale[o] = mean|W[o,:]| ; S = 512 - 2*P (P = popcount(a^wsign)) ; y = scale*S
//   bn = A*S + B2,  A = gamma*scale*r, B2 = beta - gamma*mean*r
//   t  = bn + x - shift = (-2A)*P + (512A + B2 - shift) + x = A2*P + C2 + x
//   out = max(t,0) + slope*min(t,0) + bias   (branchless RPReLU)
//
// Journal:
//   R1: nontemporal stores -> WRITE 100->238 MB + L3 eviction. Never again.
//   R2: xv[32] reg-cache defeated by remat under 64-VGPR cap (FETCH 127->64 MB,
//       dur only -4%: latency, not traffic, is the cost). 83.3 us.
//   R3: sw-pipelined phase 2 flattened by regalloc too; store/load interleave
//       thrashed L2. 113 us.
//   R4: asm-pin after the barrier: loads+pins sank past __syncthreads together
//       (x is const/__restrict) -> remat anyway, at HALF the occupancy. 97 us.
//       LESSON: the fused barrier-coupled structure cannot be made to hold x
//       in registers. ALSO: FETCH(64MB) < sizeof(x): working set is
//       L3-resident across iterations -> this is a LATENCY problem.
//   R5 (this): split into two barrier-free streaming kernels. Bits go through
//       a 3.2MB workspace array (word-major). Kernel B keeps bits in VGPRs,
//       8-load bursts with 256 VALU ops of separation, ~44 regs, no pressure,
//       no remat motive, fine-grained grid (3136 x 128thr).

__global__ __launch_bounds__(64) void precompute_kernel(
    const float* __restrict__ W,
    const float* __restrict__ bn_gamma, const float* __restrict__ bn_beta,
    const float* __restrict__ bn_mean,  const float* __restrict__ bn_var,
    const float* __restrict__ pr_slope, const float* __restrict__ pr_shift,
    const float* __restrict__ pr_bias,
    uint32_t* __restrict__ wbits, float4* __restrict__ params)
{
    const int o    = blockIdx.x;
    const int lane = threadIdx.x;
    const float4* wrow4 = (const float4*)(W + (size_t)o * C_);
    const float4 u = wrow4[2 * lane];
    const float4 v = wrow4[2 * lane + 1];

    float s = fabsf(u.x) + fabsf(u.y) + fabsf(u.z) + fabsf(u.w)
            + fabsf(v.x) + fabsf(v.y) + fabsf(v.z) + fabsf(v.w);
    for (int off = 32; off > 0; off >>= 1) s += __shfl_down(s, off, 64);

    uint32_t m8 = (u.x < 0.f ? 1u : 0u)  | (u.y < 0.f ? 2u : 0u)
                | (u.z < 0.f ? 4u : 0u)  | (u.w < 0.f ? 8u : 0u)
                | (v.x < 0.f ? 16u : 0u) | (v.y < 0.f ? 32u : 0u)
                | (v.z < 0.f ? 64u : 0u) | (v.w < 0.f ? 128u : 0u);

    const uint32_t g0 = __shfl(m8, 4 * lane + 0, 64);
    const uint32_t g1 = __shfl(m8, 4 * lane + 1, 64);
    const uint32_t g2 = __shfl(m8, 4 * lane + 2, 64);
    const uint32_t g3 = __shfl(m8, 4 * lane + 3, 64);
    if (lane < 16)
        wbits[o * 16 + lane] = g0 | (g1 << 8) | (g2 << 16) | (g3 << 24);

    if (lane == 0) {
        float scale = s * (1.0f / (float)C_);
        float r  = rsqrtf(bn_var[o] + BN_EPS);
        float A  = bn_gamma[o] * scale * r;
        float A2 = -2.0f * A;
        float C2 = (float)C_ * A + bn_beta[o] - bn_gamma[o] * bn_mean[o] * r
                 - pr_shift[o];
        params[o] = make_float4(A2, C2, pr_slope[o], pr_bias[o]);
    }
}

// ---- Kernel A: binarize. Block = 128 thr = 2 waves; wave handles one
// 64-channel chunk for 64 consecutive pairs. Grid = 784 tiles * 4 = 3136.
// No LDS, no barrier; all loads/stores coalesced (lane = consecutive pair).
__global__ __launch_bounds__(128, 8) void binarize_kernel(
    const float* __restrict__ x, const float* __restrict__ rsign_bias,
    uint32_t* __restrict__ abits_g)
{
    const int lane = threadIdx.x & 63;
    const int wv   = threadIdx.x >> 6;                    // 0..1
    const uint32_t blk  = blockIdx.x;                     // 3136
    const uint32_t tile = blk >> 2;                       // 0..783
    const uint32_t wc   = (blk & 3) * 2 + wv;             // chunk 0..7 (wave-uniform)

    const uint32_t pair = tile * 64u + (uint32_t)lane;
    const uint32_t b    = pair / 784u;                    // magic-mul div
    const uint32_t hw   = pair - b * 784u;
    const float*   xg   = x + (size_t)b * (C_ * HW_) + hw;

    const int c0 = (int)wc * 64;                          // wave-uniform

    uint32_t m0 = 0, m1 = 0;
    #pragma unroll
    for (int h = 0; h < 4; ++h) {
        float v[16];                                      // 16-deep load burst
        #pragma unroll
        for (int t = 0; t < 16; ++t)
            v[t] = xg[(size_t)(c0 + h * 16 + t) * HW_];
        #pragma unroll
        for (int t = 0; t < 16; ++t) {
            const int c = h * 16 + t;                     // 0..63 compile-time
            if (v[t] + rsign_bias[c0 + c] < 0.f) {        // bias: s_load
                if (c < 32) m0 |= (1u << c);
                else        m1 |= (1u << (c - 32));
            }
        }
    }
    // word-major: abits_g[w][pair] -> both stores coalesced (4B * 64 lanes)
    abits_g[(size_t)(2 * wc)     * NPAIR + pair] = m0;
    abits_g[(size_t)(2 * wc + 1) * NPAIR + pair] = m1;
}

// ---- Kernel B: popcount-GEMM + epilogue. Block = 128 thr = 2 waves; wave
// handles one 64-output chunk for 64 consecutive pairs. Grid = 3136.
// Bits a[16] live in REGISTERS (no LDS tile, no barrier -> nothing for the
// register allocator to fight). Inner loop: 8-load x burst, then 256 popc
// VALU ops, then consume -> ~500 cy of independent work per load batch.
// Live regs ~44 under the 64 cap (8 waves/SIMD): no spill, no remat motive.
__global__ __launch_bounds__(128, 8) void gemm_kernel(
    const float* __restrict__ x, const uint32_t* __restrict__ abits_g,
    const uint32_t* __restrict__ wbits, const float4* __restrict__ params,
    float* __restrict__ out)
{
    const int lane = threadIdx.x & 63;
    const int wv   = threadIdx.x >> 6;
    const uint32_t blk  = blockIdx.x;                     // 3136
    const uint32_t tile = blk >> 2;
    const uint32_t oc   = (blk & 3) * 2 + wv;             // o-chunk 0..7 (uniform)

    const uint32_t pair = tile * 64u + (uint32_t)lane;
    const uint32_t b    = pair / 784u;
    const uint32_t hw   = pair - b * 784u;
    const size_t   base = (size_t)b * (C_ * HW_) + hw;
    const float*   xg   = x + base;
    float*         og   = out + base;

    // full 512-bit activation row in registers: 16 coalesced dword loads
    uint32_t a[16];
    #pragma unroll
    for (int w = 0; w < 16; ++w)
        a[w] = abits_g[(size_t)w * NPAIR + pair];

    const int o0 = (int)oc * 64;                          // wave-uniform

    #pragma unroll
    for (int g = 0; g < 8; ++g) {
        float xv[8];
        int   P[8];
        #pragma unroll
        for (int u = 0; u < 8; ++u)                       // 8-load burst
            xv[u] = xg[(size_t)(o0 + g * 8 + u) * HW_];
        #pragma unroll
        for (int u = 0; u < 8; ++u) {                     // 256 VALU of cover
            const uint32_t* wr = wbits + (o0 + g * 8 + u) * 16;  // s_loads
            int p = 0;
            #pragma unroll
            for (int w = 0; w < 16; ++w) p += __popc(a[w] ^ wr[w]);
            P[u] = p;
        }
        #pragma unroll
        for (int u = 0; u < 8; ++u) {
            const int o = o0 + g * 8 + u;
            const float4 pp = params[o];                  // s_load
            const float t = fmaf(pp.x, (float)P[u], pp.y + xv[u]);
            const float r = fmaf(pp.z, fminf(t, 0.f), fmaxf(t, 0.f) + pp.w);
            og[(size_t)o * HW_] = r;                      // plain store (R1!)
        }
    }
}

// ---- Fallback fused kernel (R2 structure, 83 us measured) for the case
// ws_size < WS_NEEDED. Proven correct; only used if workspace is small.
__global__ __launch_bounds__(1024, 8) void fused_kernel(
    const float* __restrict__ x, const float* __restrict__ rsign_bias,
    const uint32_t* __restrict__ wbits, const float4* __restrict__ params,
    float* __restrict__ out)
{
    __shared__ uint32_t abits[64 * 17];

    const int i  = threadIdx.x;
    const int jj = __builtin_amdgcn_readfirstlane(threadIdx.y);

    const uint32_t pair = (uint32_t)blockIdx.x * 64u + (uint32_t)i;
    const uint32_t b    = pair / 784u;
    const uint32_t hw   = pair - b * 784u;
    const size_t   base = (size_t)b * (C_ * HW_) + hw;
    const float*   xg   = x + base;

    const int c0 = jj * 32;

    {
        float v[32];
        #pragma unroll
        for (int t = 0; t < 32; ++t)
            v[t] = xg[(size_t)(c0 + t) * HW_];
        uint32_t m = 0;
        #pragma unroll
        for (int t = 0; t < 32; ++t)
            if (v[t] + rsign_bias[c0 + t] < 0.f) m |= (1u << t);
        abits[i * 17 + jj] = m;
    }
    __syncthreads();

    uint32_t a[16];
    #pragma unroll
    for (int w = 0; w < 16; ++w) a[w] = abits[i * 17 + w];

    float* og = out + base;

    #pragma unroll
    for (int oo = 0; oo < 32; ++oo) {
        const int o = c0 + oo;
        const uint32_t* wr = wbits + o * 16;
        int P = 0;
        #pragma unroll
        for (int w = 0; w < 16; ++w) P += __popc(a[w] ^ wr[w]);

        const float4 p = params[o];
        const float t = fmaf(p.x, (float)P, p.y + xg[(size_t)o * HW_]);
        const float r = fmaf(p.z, fminf(t, 0.f), fmaxf(t, 0.f) + p.w);
        og[(size_t)o * HW_] = r;
    }
}

extern "C" void kernel_launch(void* const* d_in, const int* in_sizes, int n_in,
                              void* d_out, int out_size, void* d_ws, size_t ws_size,
                              hipStream_t stream) {
    const float* x          = (const float*)d_in[0];
    const float* rsign_bias = (const float*)d_in[1];
    const float* W          = (const float*)d_in[2];
    const float* bn_gamma   = (const float*)d_in[3];
    const float* bn_beta    = (const float*)d_in[4];
    const float* bn_mean    = (const float*)d_in[5];
    const float* bn_var     = (const float*)d_in[6];
    const float* pr_slope   = (const float*)d_in[7];
    const float* pr_shift   = (const float*)d_in[8];
    const float* pr_bias    = (const float*)d_in[9];
    float* out = (float*)d_out;

    uint32_t* wbits   = (uint32_t*)d_ws;
    float4*   params  = (float4*)((char*)d_ws + 32768);
    uint32_t* abits_g = (uint32_t*)((char*)d_ws + ABITS_OFF);

    precompute_kernel<<<dim3(C_), dim3(64), 0, stream>>>(
        W, bn_gamma, bn_beta, bn_mean, bn_var, pr_slope, pr_shift, pr_bias,
        wbits, params);

    if (ws_size >= WS_NEEDED) {
        binarize_kernel<<<dim3(3136), dim3(128), 0, stream>>>(
            x, rsign_bias, abits_g);
        gemm_kernel<<<dim3(3136), dim3(128), 0, stream>>>(
            x, abits_g, wbits, params, out);
    } else {
        fused_kernel<<<dim3(784), dim3(64, 16), 0, stream>>>(
            x, rsign_bias, wbits, params, out);
    }
}